// Round 4
// baseline (978.175 us; speedup 1.0000x reference)
//
#include <hip/hip_runtime.h>
#include <hip/hip_bf16.h>

#define NSEQ 2048
#define DM 512
#define BATCH 8
#define GTOT (BATCH * NSEQ)          // 16384
#define INV_T 0.044194173824159216f  // 1/sqrt(512)
#define EPSN 1e-5f

typedef __bf16 bf16_t;
typedef bf16_t bf16x8 __attribute__((ext_vector_type(8)));
typedef float f32x16 __attribute__((ext_vector_type(16)));
typedef unsigned short u16;
typedef unsigned int u32;

__device__ __forceinline__ u16 f2bf(float f) {
    u32 u = __builtin_bit_cast(u32, f);
    u32 r = (u + 0x7FFFu + ((u >> 16) & 1u)) >> 16;
    return (u16)r;
}

// async global->LDS DMA, 16 B per lane. LDS dest = wave-uniform base + lane*16 B.
__device__ __forceinline__ void async16(const u16* g, u16* l) {
    __builtin_amdgcn_global_load_lds(
        (const __attribute__((address_space(1))) u32*)g,
        (__attribute__((address_space(3))) u32*)l, 16, 0, 0);
}

// LDS tile: rows x 32 k-elems (64 B rows), 16-B chunks XOR-swizzled by ((row>>1)&3).
__device__ __forceinline__ bf16x8 fragld(const u16* t, int row, int kc) {
    return *(const bf16x8*)(t + row * 32 + ((kc ^ ((row >> 1) & 3)) << 3));
}

#define MFMA32(a, b, c) __builtin_amdgcn_mfma_f32_32x32x16_bf16(a, b, c, 0, 0, 0)
#define ROWOFF(reg, lh) (((reg) & 3) + 8 * ((reg) >> 2) + 4 * (lh))

// ---------------- kernel 1: f32 -> bf16 of X and W; zero ssbuf ----------------
__global__ __launch_bounds__(256) void k_convert(
    const float* __restrict__ X, const float* __restrict__ W,
    u16* __restrict__ Kbf, u16* __restrict__ Wbf, float* __restrict__ ssbuf) {
    const long NK = (long)GTOT * DM / 4;  // 2097152
    const long NW = (long)DM * DM / 4;    // 65536
    const long NS = GTOT / 4;             // 4096
    long i = (long)blockIdx.x * 256 + threadIdx.x;
    if (i < NK) {
        float4 f = ((const float4*)X)[i];
        ushort4 o;
        o.x = f2bf(f.x); o.y = f2bf(f.y); o.z = f2bf(f.z); o.w = f2bf(f.w);
        ((ushort4*)Kbf)[i] = o;
    } else if (i < NK + NW) {
        long j = i - NK;
        float4 f = ((const float4*)W)[j];
        ushort4 o;
        o.x = f2bf(f.x); o.y = f2bf(f.y); o.z = f2bf(f.z); o.w = f2bf(f.w);
        ((ushort4*)Wbf)[j] = o;
    } else if (i < NK + NW + NS) {
        ((float4*)ssbuf)[i - NK - NW] = (float4){0.f, 0.f, 0.f, 0.f};
    }
}

// --- kernel 2: S = mask .* (X X^T) * INV_T (bf16) + row sum-of-squares atomics ---
// 256x256 tile, 512 threads (8 waves = 2 My x 4 Nx, wave tile 128x64).
// Single-barrier ping-pong: DMA(kt+1) issued right after barrier publishing kt.
__global__ __launch_bounds__(512, 4) void k_sgemm(
    const u16* __restrict__ Kbf, const float* __restrict__ mask,
    u16* __restrict__ Sbuf, float* __restrict__ ssbuf) {
    __shared__ __attribute__((aligned(16))) u16 Ab[2][8192], Bb[2][8192];
    const int tid = threadIdx.x, wave = tid >> 6, lane = tid & 63;
    const int l31 = lane & 31, lh = lane >> 5;
    const int wy = wave >> 2, wx = wave & 3;
    const int b = blockIdx.z;
    const int M0 = blockIdx.y * 256, N0 = blockIdx.x * 256;
    const u16* Ag = Kbf + (long)(b * NSEQ + M0) * DM;
    const u16* Bg = Kbf + (long)(b * NSEQ + N0) * DM;

    const int u0 = wave * 2;
    const int rA0 = u0 * 16 + (lane >> 2);        // wave rows 32w..32w+15 / +16
    const int kcg = (lane & 3) ^ ((lane >> 3) & 3);
    const long aoff = (long)rA0 * DM + kcg * 8;
    const int ldst = u0 * 512 + lane * 8;

    f32x16 acc[4][2];
#pragma unroll
    for (int i = 0; i < 4; ++i)
#pragma unroll
        for (int j = 0; j < 2; ++j)
#pragma unroll
            for (int e = 0; e < 16; ++e) acc[i][j][e] = 0.f;

    // prologue: stage kt=0 into buf 0
    async16(Ag + aoff, Ab[0] + ldst);
    async16(Ag + aoff + 16 * DM, Ab[0] + ldst + 512);
    async16(Bg + aoff, Bb[0] + ldst);
    async16(Bg + aoff + 16 * DM, Bb[0] + ldst + 512);
    __syncthreads();

    for (int kt = 0; kt < 16; ++kt) {
        const int cur = kt & 1, nxt = cur ^ 1;
        if (kt < 15) {
            const long o = aoff + (kt + 1) * 32;
            async16(Ag + o, Ab[nxt] + ldst);
            async16(Ag + o + 16 * DM, Ab[nxt] + ldst + 512);
            async16(Bg + o, Bb[nxt] + ldst);
            async16(Bg + o + 16 * DM, Bb[nxt] + ldst + 512);
        }
#pragma unroll
        for (int ks = 0; ks < 2; ++ks) {
            const int kc = ks * 2 + lh;
            bf16x8 a0 = fragld(Ab[cur], wy * 128 + l31, kc);
            bf16x8 a1 = fragld(Ab[cur], wy * 128 + 32 + l31, kc);
            bf16x8 a2 = fragld(Ab[cur], wy * 128 + 64 + l31, kc);
            bf16x8 a3 = fragld(Ab[cur], wy * 128 + 96 + l31, kc);
            bf16x8 b0 = fragld(Bb[cur], wx * 64 + l31, kc);
            bf16x8 b1 = fragld(Bb[cur], wx * 64 + 32 + l31, kc);
            acc[0][0] = MFMA32(a0, b0, acc[0][0]);
            acc[0][1] = MFMA32(a0, b1, acc[0][1]);
            acc[1][0] = MFMA32(a1, b0, acc[1][0]);
            acc[1][1] = MFMA32(a1, b1, acc[1][1]);
            acc[2][0] = MFMA32(a2, b0, acc[2][0]);
            acc[2][1] = MFMA32(a2, b1, acc[2][1]);
            acc[3][0] = MFMA32(a3, b0, acc[3][0]);
            acc[3][1] = MFMA32(a3, b1, acc[3][1]);
        }
        __syncthreads();  // publishes buf nxt; all reads of cur done
    }
    // epilogue: mask multiply, bf16 store, per-row sum-of-squares -> atomicAdd
#pragma unroll
    for (int mi = 0; mi < 4; ++mi) {
#pragma unroll
        for (int reg = 0; reg < 16; ++reg) {
            long rg = (long)b * NSEQ + M0 + wy * 128 + mi * 32 + ROWOFF(reg, lh);
            float v = 0.f;
#pragma unroll
            for (int ni = 0; ni < 2; ++ni) {
                int cg = N0 + wx * 64 + ni * 32 + l31;
                float s = acc[mi][ni][reg] * INV_T * mask[rg * NSEQ + cg];
                v += s * s;
                Sbuf[rg * NSEQ + cg] = f2bf(s);
            }
            v += __shfl_xor(v, 1, 32);
            v += __shfl_xor(v, 2, 32);
            v += __shfl_xor(v, 4, 32);
            v += __shfl_xor(v, 8, 32);
            v += __shfl_xor(v, 16, 32);
            if (l31 == 0) atomicAdd(&ssbuf[rg], v);
        }
    }
}

// ------------- kernel 3: vT[e][g] = elu(W X^T + b), 128x128 ping-pong -------------
// M = 512 (e), N = 16384 (g), K = 512. 4 waves = 2x2, wave tile 64x64.
__global__ __launch_bounds__(256, 4) void k_vgemm(
    const u16* __restrict__ Wbf, const u16* __restrict__ Kbf,
    const float* __restrict__ bias, u16* __restrict__ vT) {
    __shared__ __attribute__((aligned(16))) u16 Ab[2][4096], Bb[2][4096];
    const int tid = threadIdx.x, wave = tid >> 6, lane = tid & 63;
    const int l31 = lane & 31, lh = lane >> 5;
    const int wy = wave >> 1, wx = wave & 1;
    const int M0 = blockIdx.y * 128, N0 = blockIdx.x * 128;
    const u16* Ag = Wbf + (long)M0 * DM;
    const u16* Bg = Kbf + (long)N0 * DM;

    const int u0 = wave * 2;
    const int rA0 = u0 * 16 + (lane >> 2);
    const int kcg = (lane & 3) ^ ((lane >> 3) & 3);
    const long aoff = (long)rA0 * DM + kcg * 8;
    const int ldst = u0 * 512 + lane * 8;

    f32x16 acc[2][2];
#pragma unroll
    for (int i = 0; i < 2; ++i)
#pragma unroll
        for (int j = 0; j < 2; ++j)
#pragma unroll
            for (int e = 0; e < 16; ++e) acc[i][j][e] = 0.f;

    async16(Ag + aoff, Ab[0] + ldst);
    async16(Ag + aoff + 16 * DM, Ab[0] + ldst + 512);
    async16(Bg + aoff, Bb[0] + ldst);
    async16(Bg + aoff + 16 * DM, Bb[0] + ldst + 512);
    __syncthreads();

    for (int kt = 0; kt < 16; ++kt) {
        const int cur = kt & 1, nxt = cur ^ 1;
        if (kt < 15) {
            const long o = aoff + (kt + 1) * 32;
            async16(Ag + o, Ab[nxt] + ldst);
            async16(Ag + o + 16 * DM, Ab[nxt] + ldst + 512);
            async16(Bg + o, Bb[nxt] + ldst);
            async16(Bg + o + 16 * DM, Bb[nxt] + ldst + 512);
        }
#pragma unroll
        for (int ks = 0; ks < 2; ++ks) {
            const int kc = ks * 2 + lh;
            bf16x8 a0 = fragld(Ab[cur], wy * 64 + l31, kc);
            bf16x8 a1 = fragld(Ab[cur], wy * 64 + 32 + l31, kc);
            bf16x8 b0 = fragld(Bb[cur], wx * 64 + l31, kc);
            bf16x8 b1 = fragld(Bb[cur], wx * 64 + 32 + l31, kc);
            acc[0][0] = MFMA32(a0, b0, acc[0][0]);
            acc[0][1] = MFMA32(a0, b1, acc[0][1]);
            acc[1][0] = MFMA32(a1, b0, acc[1][0]);
            acc[1][1] = MFMA32(a1, b1, acc[1][1]);
        }
        __syncthreads();
    }
#pragma unroll
    for (int mi = 0; mi < 2; ++mi) {
#pragma unroll
        for (int reg = 0; reg < 16; ++reg) {
            int e = M0 + wy * 64 + mi * 32 + ROWOFF(reg, lh);
            float bv = bias[e];
#pragma unroll
            for (int ni = 0; ni < 2; ++ni) {
                int g = N0 + wx * 64 + ni * 32 + l31;
                float x = acc[mi][ni][reg] + bv;
                float v = x > 0.f ? x : (__expf(x) - 1.f);
                vT[(long)e * GTOT + g] = f2bf(v);
            }
        }
    }
}

// -------- kernel 4: O = diag(1/max(||S_row||,eps)) * (S V), 128x128 ping-pong ---------
// Per batch: M = 2048, N = 512 (d), K = 2048. A = S (bf16), B^T = vT.
__global__ __launch_bounds__(256, 4) void k_pv(
    const u16* __restrict__ Sbuf, const u16* __restrict__ vT,
    const float* __restrict__ ssbuf, float* __restrict__ Out) {
    __shared__ __attribute__((aligned(16))) u16 Ab[2][4096], Bb[2][4096];
    __shared__ float sc[128];
    const int tid = threadIdx.x, wave = tid >> 6, lane = tid & 63;
    const int l31 = lane & 31, lh = lane >> 5;
    const int wy = wave >> 1, wx = wave & 1;
    const int b = blockIdx.z;
    const int M0 = blockIdx.y * 128, N0 = blockIdx.x * 128;
    const u16* Ag = Sbuf + (long)(b * NSEQ + M0) * NSEQ;
    const u16* Bg = vT + (long)N0 * GTOT + b * NSEQ;

    if (tid < 128) {
        float v = ssbuf[b * NSEQ + M0 + tid];
        sc[tid] = 1.f / fmaxf(sqrtf(v), EPSN);
    }

    const int u0 = wave * 2;
    const int rA0 = u0 * 16 + (lane >> 2);
    const int kcg = (lane & 3) ^ ((lane >> 3) & 3);
    const long aoff = (long)rA0 * NSEQ + kcg * 8;
    const long boff = (long)rA0 * GTOT + kcg * 8;
    const int ldst = u0 * 512 + lane * 8;

    f32x16 acc[2][2];
#pragma unroll
    for (int i = 0; i < 2; ++i)
#pragma unroll
        for (int j = 0; j < 2; ++j)
#pragma unroll
            for (int e = 0; e < 16; ++e) acc[i][j][e] = 0.f;

    async16(Ag + aoff, Ab[0] + ldst);
    async16(Ag + aoff + 16 * NSEQ, Ab[0] + ldst + 512);
    async16(Bg + boff, Bb[0] + ldst);
    async16(Bg + boff + 16 * GTOT, Bb[0] + ldst + 512);
    __syncthreads();

    for (int kt = 0; kt < 64; ++kt) {
        const int cur = kt & 1, nxt = cur ^ 1;
        if (kt < 63) {
            const long oa = aoff + (kt + 1) * 32;
            const long ob = boff + (kt + 1) * 32;
            async16(Ag + oa, Ab[nxt] + ldst);
            async16(Ag + oa + 16 * NSEQ, Ab[nxt] + ldst + 512);
            async16(Bg + ob, Bb[nxt] + ldst);
            async16(Bg + ob + 16 * GTOT, Bb[nxt] + ldst + 512);
        }
#pragma unroll
        for (int ks = 0; ks < 2; ++ks) {
            const int kc = ks * 2 + lh;
            bf16x8 a0 = fragld(Ab[cur], wy * 64 + l31, kc);
            bf16x8 a1 = fragld(Ab[cur], wy * 64 + 32 + l31, kc);
            bf16x8 b0 = fragld(Bb[cur], wx * 64 + l31, kc);
            bf16x8 b1 = fragld(Bb[cur], wx * 64 + 32 + l31, kc);
            acc[0][0] = MFMA32(a0, b0, acc[0][0]);
            acc[0][1] = MFMA32(a0, b1, acc[0][1]);
            acc[1][0] = MFMA32(a1, b0, acc[1][0]);
            acc[1][1] = MFMA32(a1, b1, acc[1][1]);
        }
        __syncthreads();
    }
#pragma unroll
    for (int mi = 0; mi < 2; ++mi) {
#pragma unroll
        for (int reg = 0; reg < 16; ++reg) {
            int rl = wy * 64 + mi * 32 + ROWOFF(reg, lh);
            float s = sc[rl];
            float* op = Out + ((long)b * NSEQ + M0 + rl) * DM;
#pragma unroll
            for (int ni = 0; ni < 2; ++ni) {
                int d = N0 + wx * 64 + ni * 32 + l31;
                op[d] = acc[mi][ni][reg] * s;
            }
        }
    }
}

extern "C" void kernel_launch(void* const* d_in, const int* in_sizes, int n_in,
                              void* d_out, int out_size, void* d_ws, size_t ws_size,
                              hipStream_t stream) {
    const float* X = (const float*)d_in[0];
    const float* mask = (const float*)d_in[1];
    const float* W = (const float*)d_in[2];
    const float* bias = (const float*)d_in[3];
    float* out = (float*)d_out;

    char* ws = (char*)d_ws;
    u16* Kbf = (u16*)ws;                           // 16 MiB
    u16* Wbf = (u16*)(ws + 16777216);              // 512 KiB
    u16* vT = (u16*)(ws + 17301504);               // 16 MiB
    u16* Sbuf = (u16*)(ws + 34078720);             // 64 MiB
    float* ssbuf = (float*)(ws + 101187584);       // 64 KiB

    k_convert<<<8464, 256, 0, stream>>>(X, W, Kbf, Wbf, ssbuf);
    k_vgemm<<<dim3(128, 4), 256, 0, stream>>>(Wbf, Kbf, bias, vT);
    k_sgemm<<<dim3(8, 8, 8), 512, 0, stream>>>(Kbf, mask, Sbuf, ssbuf);
    k_pv<<<dim3(4, 16, 8), 256, 0, stream>>>(Sbuf, vT, ssbuf, out);
}

// Round 5
// 401.054 us; speedup vs baseline: 2.4390x; 2.4390x over previous
//
#include <hip/hip_runtime.h>
#include <hip/hip_bf16.h>

#define NSEQ 2048
#define DM 512
#define BATCH 8
#define GTOT (BATCH * NSEQ)          // 16384
#define INV_T 0.044194173824159216f  // 1/sqrt(512)
#define EPSN 1e-5f

typedef __bf16 bf16_t;
typedef bf16_t bf16x8 __attribute__((ext_vector_type(8)));
typedef float f32x16 __attribute__((ext_vector_type(16)));
typedef unsigned short u16;
typedef unsigned int u32;

__device__ __forceinline__ u16 f2bf(float f) {
    u32 u = __builtin_bit_cast(u32, f);
    u32 r = (u + 0x7FFFu + ((u >> 16) & 1u)) >> 16;
    return (u16)r;
}

// async global->LDS DMA, 16 B per lane. LDS dest = wave-uniform base + lane*16 B.
__device__ __forceinline__ void async16(const u16* g, u16* l) {
    __builtin_amdgcn_global_load_lds(
        (const __attribute__((address_space(1))) u32*)g,
        (__attribute__((address_space(3))) u32*)l, 16, 0, 0);
}

// LDS tile: rows x 32 k-elems (64 B rows), 16-B chunks XOR-swizzled by ((row>>1)&3).
__device__ __forceinline__ bf16x8 fragld(const u16* t, int row, int kc) {
    return *(const bf16x8*)(t + row * 32 + ((kc ^ ((row >> 1) & 3)) << 3));
}

#define MFMA32(a, b, c) __builtin_amdgcn_mfma_f32_32x32x16_bf16(a, b, c, 0, 0, 0)
#define ROWOFF(reg, lh) (((reg) & 3) + 8 * ((reg) >> 2) + 4 * (lh))

// ---------------- kernel 1: f32 -> bf16 of X and W; zero ssbuf ----------------
__global__ __launch_bounds__(256) void k_convert(
    const float* __restrict__ X, const float* __restrict__ W,
    u16* __restrict__ Kbf, u16* __restrict__ Wbf, float* __restrict__ ssbuf) {
    const long NK = (long)GTOT * DM / 4;  // 2097152
    const long NW = (long)DM * DM / 4;    // 65536
    const long NS = GTOT / 4;             // 4096
    long i = (long)blockIdx.x * 256 + threadIdx.x;
    if (i < NK) {
        float4 f = ((const float4*)X)[i];
        ushort4 o;
        o.x = f2bf(f.x); o.y = f2bf(f.y); o.z = f2bf(f.z); o.w = f2bf(f.w);
        ((ushort4*)Kbf)[i] = o;
    } else if (i < NK + NW) {
        long j = i - NK;
        float4 f = ((const float4*)W)[j];
        ushort4 o;
        o.x = f2bf(f.x); o.y = f2bf(f.y); o.z = f2bf(f.z); o.w = f2bf(f.w);
        ((ushort4*)Wbf)[j] = o;
    } else if (i < NK + NW + NS) {
        ((float4*)ssbuf)[i - NK - NW] = (float4){0.f, 0.f, 0.f, 0.f};
    }
}

// --- kernel 2: S = mask .* (X X^T) * INV_T (bf16) + row sum-of-squares atomics ---
// 256x256 tile, 512 threads (8 waves = 2 My x 4 Nx, wave tile 128x64).
// Single-barrier ping-pong. lb(512,2): 256-reg cap -> NO SPILL (128 acc + ~60 work).
__global__ __launch_bounds__(512, 2) void k_sgemm(
    const u16* __restrict__ Kbf, const float* __restrict__ mask,
    u16* __restrict__ Sbuf, float* __restrict__ ssbuf) {
    __shared__ __attribute__((aligned(16))) u16 Ab[2][8192], Bb[2][8192];
    const int tid = threadIdx.x, wave = tid >> 6, lane = tid & 63;
    const int l31 = lane & 31, lh = lane >> 5;
    const int wy = wave >> 2, wx = wave & 3;
    const int b = blockIdx.z;
    const int M0 = blockIdx.y * 256, N0 = blockIdx.x * 256;
    const u16* Ag = Kbf + (long)(b * NSEQ + M0) * DM;
    const u16* Bg = Kbf + (long)(b * NSEQ + N0) * DM;

    const int u0 = wave * 2;
    const int rA0 = u0 * 16 + (lane >> 2);        // wave rows 32w..32w+15 / +16
    const int kcg = (lane & 3) ^ ((lane >> 3) & 3);
    const long aoff = (long)rA0 * DM + kcg * 8;
    const int ldst = u0 * 512 + lane * 8;

    f32x16 acc[4][2];
#pragma unroll
    for (int i = 0; i < 4; ++i)
#pragma unroll
        for (int j = 0; j < 2; ++j)
#pragma unroll
            for (int e = 0; e < 16; ++e) acc[i][j][e] = 0.f;

    // prologue: stage kt=0 into buf 0
    async16(Ag + aoff, Ab[0] + ldst);
    async16(Ag + aoff + 16 * DM, Ab[0] + ldst + 512);
    async16(Bg + aoff, Bb[0] + ldst);
    async16(Bg + aoff + 16 * DM, Bb[0] + ldst + 512);
    __syncthreads();

    for (int kt = 0; kt < 16; ++kt) {
        const int cur = kt & 1, nxt = cur ^ 1;
        if (kt < 15) {
            const long o = aoff + (kt + 1) * 32;
            async16(Ag + o, Ab[nxt] + ldst);
            async16(Ag + o + 16 * DM, Ab[nxt] + ldst + 512);
            async16(Bg + o, Bb[nxt] + ldst);
            async16(Bg + o + 16 * DM, Bb[nxt] + ldst + 512);
        }
#pragma unroll
        for (int ks = 0; ks < 2; ++ks) {
            const int kc = ks * 2 + lh;
            bf16x8 a0 = fragld(Ab[cur], wy * 128 + l31, kc);
            bf16x8 a1 = fragld(Ab[cur], wy * 128 + 32 + l31, kc);
            bf16x8 a2 = fragld(Ab[cur], wy * 128 + 64 + l31, kc);
            bf16x8 a3 = fragld(Ab[cur], wy * 128 + 96 + l31, kc);
            bf16x8 b0 = fragld(Bb[cur], wx * 64 + l31, kc);
            bf16x8 b1 = fragld(Bb[cur], wx * 64 + 32 + l31, kc);
            acc[0][0] = MFMA32(a0, b0, acc[0][0]);
            acc[0][1] = MFMA32(a0, b1, acc[0][1]);
            acc[1][0] = MFMA32(a1, b0, acc[1][0]);
            acc[1][1] = MFMA32(a1, b1, acc[1][1]);
            acc[2][0] = MFMA32(a2, b0, acc[2][0]);
            acc[2][1] = MFMA32(a2, b1, acc[2][1]);
            acc[3][0] = MFMA32(a3, b0, acc[3][0]);
            acc[3][1] = MFMA32(a3, b1, acc[3][1]);
        }
        __syncthreads();  // publishes buf nxt; all reads of cur done
    }
    // epilogue: mask multiply, bf16 store, per-row sum-of-squares -> atomicAdd
#pragma unroll
    for (int mi = 0; mi < 4; ++mi) {
#pragma unroll
        for (int reg = 0; reg < 16; ++reg) {
            long rg = (long)b * NSEQ + M0 + wy * 128 + mi * 32 + ROWOFF(reg, lh);
            float v = 0.f;
#pragma unroll
            for (int ni = 0; ni < 2; ++ni) {
                int cg = N0 + wx * 64 + ni * 32 + l31;
                float s = acc[mi][ni][reg] * INV_T * mask[rg * NSEQ + cg];
                v += s * s;
                Sbuf[rg * NSEQ + cg] = f2bf(s);
            }
            v += __shfl_xor(v, 1, 32);
            v += __shfl_xor(v, 2, 32);
            v += __shfl_xor(v, 4, 32);
            v += __shfl_xor(v, 8, 32);
            v += __shfl_xor(v, 16, 32);
            if (l31 == 0) atomicAdd(&ssbuf[rg], v);
        }
    }
}

// ------------- kernel 3: vT[e][g] = elu(W X^T + b), 128x128 ping-pong -------------
__global__ __launch_bounds__(256, 4) void k_vgemm(
    const u16* __restrict__ Wbf, const u16* __restrict__ Kbf,
    const float* __restrict__ bias, u16* __restrict__ vT) {
    __shared__ __attribute__((aligned(16))) u16 Ab[2][4096], Bb[2][4096];
    const int tid = threadIdx.x, wave = tid >> 6, lane = tid & 63;
    const int l31 = lane & 31, lh = lane >> 5;
    const int wy = wave >> 1, wx = wave & 1;
    const int M0 = blockIdx.y * 128, N0 = blockIdx.x * 128;
    const u16* Ag = Wbf + (long)M0 * DM;
    const u16* Bg = Kbf + (long)N0 * DM;

    const int u0 = wave * 2;
    const int rA0 = u0 * 16 + (lane >> 2);
    const int kcg = (lane & 3) ^ ((lane >> 3) & 3);
    const long aoff = (long)rA0 * DM + kcg * 8;
    const int ldst = u0 * 512 + lane * 8;

    f32x16 acc[2][2];
#pragma unroll
    for (int i = 0; i < 2; ++i)
#pragma unroll
        for (int j = 0; j < 2; ++j)
#pragma unroll
            for (int e = 0; e < 16; ++e) acc[i][j][e] = 0.f;

    async16(Ag + aoff, Ab[0] + ldst);
    async16(Ag + aoff + 16 * DM, Ab[0] + ldst + 512);
    async16(Bg + aoff, Bb[0] + ldst);
    async16(Bg + aoff + 16 * DM, Bb[0] + ldst + 512);
    __syncthreads();

    for (int kt = 0; kt < 16; ++kt) {
        const int cur = kt & 1, nxt = cur ^ 1;
        if (kt < 15) {
            const long o = aoff + (kt + 1) * 32;
            async16(Ag + o, Ab[nxt] + ldst);
            async16(Ag + o + 16 * DM, Ab[nxt] + ldst + 512);
            async16(Bg + o, Bb[nxt] + ldst);
            async16(Bg + o + 16 * DM, Bb[nxt] + ldst + 512);
        }
#pragma unroll
        for (int ks = 0; ks < 2; ++ks) {
            const int kc = ks * 2 + lh;
            bf16x8 a0 = fragld(Ab[cur], wy * 64 + l31, kc);
            bf16x8 a1 = fragld(Ab[cur], wy * 64 + 32 + l31, kc);
            bf16x8 b0 = fragld(Bb[cur], wx * 64 + l31, kc);
            bf16x8 b1 = fragld(Bb[cur], wx * 64 + 32 + l31, kc);
            acc[0][0] = MFMA32(a0, b0, acc[0][0]);
            acc[0][1] = MFMA32(a0, b1, acc[0][1]);
            acc[1][0] = MFMA32(a1, b0, acc[1][0]);
            acc[1][1] = MFMA32(a1, b1, acc[1][1]);
        }
        __syncthreads();
    }
#pragma unroll
    for (int mi = 0; mi < 2; ++mi) {
#pragma unroll
        for (int reg = 0; reg < 16; ++reg) {
            int e = M0 + wy * 64 + mi * 32 + ROWOFF(reg, lh);
            float bv = bias[e];
#pragma unroll
            for (int ni = 0; ni < 2; ++ni) {
                int g = N0 + wx * 64 + ni * 32 + l31;
                float x = acc[mi][ni][reg] + bv;
                float v = x > 0.f ? x : (__expf(x) - 1.f);
                vT[(long)e * GTOT + g] = f2bf(v);
            }
        }
    }
}

// -------- kernel 4: O = diag(1/max(||S_row||,eps)) * (S V), 256x128 ping-pong ---------
// Per batch: M = 2048 (rows), N = 512 (d), K = 2048. A = S (bf16), B^T = vT.
// 512 threads, 8 waves = 4 My x 2 Nx, wave tile 64x64. acc 64 f32 -> lb(512,4) ok.
__global__ __launch_bounds__(512, 4) void k_pv(
    const u16* __restrict__ Sbuf, const u16* __restrict__ vT,
    const float* __restrict__ ssbuf, float* __restrict__ Out) {
    __shared__ __attribute__((aligned(16))) u16 Ab[2][8192], Bb[2][4096];
    __shared__ float sc[256];
    const int tid = threadIdx.x, wave = tid >> 6, lane = tid & 63;
    const int l31 = lane & 31, lh = lane >> 5;
    const int wy = wave >> 1, wx = wave & 1;
    const int b = blockIdx.z;
    const int M0 = blockIdx.y * 256, N0 = blockIdx.x * 128;
    const u16* Ag = Sbuf + (long)(b * NSEQ + M0) * NSEQ;
    const u16* Bg = vT + (long)N0 * GTOT + b * NSEQ;

    if (tid < 256) {
        float v = ssbuf[b * NSEQ + M0 + tid];
        sc[tid] = 1.f / fmaxf(sqrtf(v), EPSN);
    }

    const int u0 = wave * 2;
    const int rA0 = u0 * 16 + (lane >> 2);    // 0..255 over 8 waves x 2 issues
    const int rB0 = wave * 16 + (lane >> 2);  // 0..127 over 8 waves x 1 issue
    const int kcg = (lane & 3) ^ ((lane >> 3) & 3);
    const long aoff = (long)rA0 * NSEQ + kcg * 8;
    const long boff = (long)rB0 * GTOT + kcg * 8;
    const int ldstA = u0 * 512 + lane * 8;
    const int ldstB = wave * 512 + lane * 8;

    f32x16 acc[2][2];
#pragma unroll
    for (int i = 0; i < 2; ++i)
#pragma unroll
        for (int j = 0; j < 2; ++j)
#pragma unroll
            for (int e = 0; e < 16; ++e) acc[i][j][e] = 0.f;

    async16(Ag + aoff, Ab[0] + ldstA);
    async16(Ag + aoff + 16 * NSEQ, Ab[0] + ldstA + 512);
    async16(Bg + boff, Bb[0] + ldstB);
    __syncthreads();

    for (int kt = 0; kt < 64; ++kt) {
        const int cur = kt & 1, nxt = cur ^ 1;
        if (kt < 63) {
            const long oa = aoff + (kt + 1) * 32;
            const long ob = boff + (kt + 1) * 32;
            async16(Ag + oa, Ab[nxt] + ldstA);
            async16(Ag + oa + 16 * NSEQ, Ab[nxt] + ldstA + 512);
            async16(Bg + ob, Bb[nxt] + ldstB);
        }
#pragma unroll
        for (int ks = 0; ks < 2; ++ks) {
            const int kc = ks * 2 + lh;
            bf16x8 a0 = fragld(Ab[cur], wy * 64 + l31, kc);
            bf16x8 a1 = fragld(Ab[cur], wy * 64 + 32 + l31, kc);
            bf16x8 b0 = fragld(Bb[cur], wx * 64 + l31, kc);
            bf16x8 b1 = fragld(Bb[cur], wx * 64 + 32 + l31, kc);
            acc[0][0] = MFMA32(a0, b0, acc[0][0]);
            acc[0][1] = MFMA32(a0, b1, acc[0][1]);
            acc[1][0] = MFMA32(a1, b0, acc[1][0]);
            acc[1][1] = MFMA32(a1, b1, acc[1][1]);
        }
        __syncthreads();
    }
#pragma unroll
    for (int mi = 0; mi < 2; ++mi) {
#pragma unroll
        for (int reg = 0; reg < 16; ++reg) {
            int rl = wy * 64 + mi * 32 + ROWOFF(reg, lh);
            float s = sc[rl];
            float* op = Out + ((long)b * NSEQ + M0 + rl) * DM;
#pragma unroll
            for (int ni = 0; ni < 2; ++ni) {
                int d = N0 + wx * 64 + ni * 32 + l31;
                op[d] = acc[mi][ni][reg] * s;
            }
        }
    }
}

extern "C" void kernel_launch(void* const* d_in, const int* in_sizes, int n_in,
                              void* d_out, int out_size, void* d_ws, size_t ws_size,
                              hipStream_t stream) {
    const float* X = (const float*)d_in[0];
    const float* mask = (const float*)d_in[1];
    const float* W = (const float*)d_in[2];
    const float* bias = (const float*)d_in[3];
    float* out = (float*)d_out;

    char* ws = (char*)d_ws;
    u16* Kbf = (u16*)ws;                           // 16 MiB
    u16* Wbf = (u16*)(ws + 16777216);              // 512 KiB
    u16* vT = (u16*)(ws + 17301504);               // 16 MiB
    u16* Sbuf = (u16*)(ws + 34078720);             // 64 MiB
    float* ssbuf = (float*)(ws + 101187584);       // 64 KiB

    k_convert<<<8464, 256, 0, stream>>>(X, W, Kbf, Wbf, ssbuf);
    k_vgemm<<<dim3(128, 4), 256, 0, stream>>>(Wbf, Kbf, bias, vT);
    k_sgemm<<<dim3(8, 8, 8), 512, 0, stream>>>(Kbf, mask, Sbuf, ssbuf);
    k_pv<<<dim3(4, 8, 8), 512, 0, stream>>>(Sbuf, vT, ssbuf, out);
}

// Round 6
// 370.930 us; speedup vs baseline: 2.6371x; 1.0812x over previous
//
#include <hip/hip_runtime.h>
#include <hip/hip_bf16.h>

#define NSEQ 2048
#define DM 512
#define BATCH 8
#define GTOT (BATCH * NSEQ)          // 16384
#define INV_T 0.044194173824159216f  // 1/sqrt(512)
#define EPSN 1e-5f

typedef __bf16 bf16_t;
typedef bf16_t bf16x8 __attribute__((ext_vector_type(8)));
typedef float f32x16 __attribute__((ext_vector_type(16)));
typedef unsigned short u16;
typedef unsigned int u32;
typedef unsigned long long u64;

__device__ __forceinline__ u16 f2bf(float f) {
    u32 u = __builtin_bit_cast(u32, f);
    u32 r = (u + 0x7FFFu + ((u >> 16) & 1u)) >> 16;
    return (u16)r;
}

// async global->LDS DMA, 16 B per lane. LDS dest = wave-uniform base + lane*16 B.
__device__ __forceinline__ void async16(const u16* g, u16* l) {
    __builtin_amdgcn_global_load_lds(
        (const __attribute__((address_space(1))) u32*)g,
        (__attribute__((address_space(3))) u32*)l, 16, 0, 0);
}

// LDS tile: rows x 32 k-elems (64 B rows), 16-B chunks XOR-swizzled by ((row>>1)&3).
__device__ __forceinline__ bf16x8 fragld(const u16* t, int row, int kc) {
    return *(const bf16x8*)(t + row * 32 + ((kc ^ ((row >> 1) & 3)) << 3));
}

#define MFMA32(a, b, c) __builtin_amdgcn_mfma_f32_32x32x16_bf16(a, b, c, 0, 0, 0)
#define ROWOFF(reg, lh) (((reg) & 3) + 8 * ((reg) >> 2) + 4 * (lh))

// Staging: 4 issues per thread (2 A + 2 B), swizzled chunk on global side.
#define STAGE(Ag, ldA, Bg, ldB, k0)                                                    \
    do {                                                                               \
        async16((Ag) + (long)rA0 * (ldA) + (k0) + kcg * 8, Ab + u0 * 512 + lane * 8);  \
        async16((Ag) + (long)(rA0 + 16) * (ldA) + (k0) + kcg * 8, Ab + (u0 + 1) * 512 + lane * 8); \
        async16((Bg) + (long)rA0 * (ldB) + (k0) + kcg * 8, Bb + u0 * 512 + lane * 8);  \
        async16((Bg) + (long)(rA0 + 16) * (ldB) + (k0) + kcg * 8, Bb + (u0 + 1) * 512 + lane * 8); \
    } while (0)

// ---- kernel 1: f32 -> bf16 of X and W; zero ssbuf; bit-pack mask via ballot ----
__global__ __launch_bounds__(256) void k_convert(
    const float* __restrict__ X, const float* __restrict__ W,
    const float* __restrict__ mask,
    u16* __restrict__ Kbf, u16* __restrict__ Wbf,
    float* __restrict__ ssbuf, u64* __restrict__ Mbits) {
    const long NK = (long)GTOT * DM / 4;  // 2097152 float4 groups
    const long NW = (long)DM * DM / 4;    // 65536
    const long NS = GTOT / 4;             // 4096
    const long NM = (long)BATCH * NSEQ * NSEQ / 4;  // 8388608 (4 mask elems/thread)
    long i = (long)blockIdx.x * 256 + threadIdx.x;
    if (i < NK) {
        float4 f = ((const float4*)X)[i];
        ushort4 o;
        o.x = f2bf(f.x); o.y = f2bf(f.y); o.z = f2bf(f.z); o.w = f2bf(f.w);
        ((ushort4*)Kbf)[i] = o;
    } else if (i < NK + NW) {
        long j = i - NK;
        float4 f = ((const float4*)W)[j];
        ushort4 o;
        o.x = f2bf(f.x); o.y = f2bf(f.y); o.z = f2bf(f.z); o.w = f2bf(f.w);
        ((ushort4*)Wbf)[j] = o;
    } else if (i < NK + NW + NS) {
        ((float4*)ssbuf)[i - NK - NW] = (float4){0.f, 0.f, 0.f, 0.f};
    } else if (i < NK + NW + NS + NM) {
        // wave-cooperative bit-pack: each wave packs 256 consecutive mask elems
        long j4 = i - NK - NW - NS;          // wave-aligned region
        int lane = threadIdx.x & 63;
        long wb = (j4 >> 6) << 6;            // first j4 of this wave
        long elembase = wb * 4;
#pragma unroll
        for (int it = 0; it < 4; ++it) {
            float f = mask[elembase + it * 64 + lane];
            u64 bb = __ballot(f != 0.f);
            if (lane == 0) Mbits[((wb >> 6) << 2) + it] = bb;
        }
    }
}

// --- kernel 2: S = bitmask .* (X X^T) * INV_T (bf16) + row sum-of-squares ---
// 128x128 tile, 256 thr, 4 waves (2x2), wave tile 64x64. R3-proven structure.
__global__ __launch_bounds__(256, 4) void k_sgemm(
    const u16* __restrict__ Kbf, const u32* __restrict__ Mw,
    u16* __restrict__ Sbuf, float* __restrict__ ssbuf) {
    __shared__ __attribute__((aligned(16))) u16 Ab[4096], Bb[4096];
    const int tid = threadIdx.x, wave = tid >> 6, lane = tid & 63;
    const int l31 = lane & 31, lh = lane >> 5;
    const int wy = wave >> 1, wx = wave & 1;
    const int b = blockIdx.z;
    const int M0 = blockIdx.y * 128, N0 = blockIdx.x * 128;
    const u16* Ag = Kbf + (long)(b * NSEQ + M0) * DM;
    const u16* Bg = Kbf + (long)(b * NSEQ + N0) * DM;
    const u32* Mb = Mw + (long)b * NSEQ * 64;  // 64 u32 words per row

    const int u0 = wave * 2;
    const int rA0 = u0 * 16 + (lane >> 2);
    const int kcg = (lane & 3) ^ ((lane >> 3) & 3);

    f32x16 acc[2][2];
#pragma unroll
    for (int i = 0; i < 2; ++i)
#pragma unroll
        for (int j = 0; j < 2; ++j)
#pragma unroll
            for (int e = 0; e < 16; ++e) acc[i][j][e] = 0.f;

    for (int kt = 0; kt < 16; ++kt) {
        const int k0 = kt * 32;
        __syncthreads();
        STAGE(Ag, DM, Bg, DM, k0);
        __syncthreads();
#pragma unroll
        for (int ks = 0; ks < 2; ++ks) {
            const int kc = ks * 2 + lh;
            bf16x8 a0 = fragld(Ab, wy * 64 + l31, kc);
            bf16x8 a1 = fragld(Ab, wy * 64 + 32 + l31, kc);
            bf16x8 b0 = fragld(Bb, wx * 64 + l31, kc);
            bf16x8 b1 = fragld(Bb, wx * 64 + 32 + l31, kc);
            acc[0][0] = MFMA32(a0, b0, acc[0][0]);
            acc[0][1] = MFMA32(a0, b1, acc[0][1]);
            acc[1][0] = MFMA32(a1, b0, acc[1][0]);
            acc[1][1] = MFMA32(a1, b1, acc[1][1]);
        }
    }
    // epilogue: bitmask multiply, bf16 store, per-row sum-of-squares -> atomicAdd
#pragma unroll
    for (int mi = 0; mi < 2; ++mi) {
#pragma unroll
        for (int reg = 0; reg < 16; ++reg) {
            int rl = M0 + wy * 64 + mi * 32 + ROWOFF(reg, lh);
            long rg = (long)b * NSEQ + rl;
            float v = 0.f;
#pragma unroll
            for (int ni = 0; ni < 2; ++ni) {
                int cg = N0 + wx * 64 + ni * 32 + l31;
                u32 w = Mb[(long)rl * 64 + (cg >> 5)];
                float s = ((w >> l31) & 1u) ? acc[mi][ni][reg] * INV_T : 0.f;
                v += s * s;
                Sbuf[rg * NSEQ + cg] = f2bf(s);
            }
            v += __shfl_xor(v, 1, 32);
            v += __shfl_xor(v, 2, 32);
            v += __shfl_xor(v, 4, 32);
            v += __shfl_xor(v, 8, 32);
            v += __shfl_xor(v, 16, 32);
            if (l31 == 0) atomicAdd(&ssbuf[rg], v);
        }
    }
}

// ------------- kernel 3: vT[e][g] = elu(W X^T + b), 128x128 R3 structure -------------
__global__ __launch_bounds__(256, 4) void k_vgemm(
    const u16* __restrict__ Wbf, const u16* __restrict__ Kbf,
    const float* __restrict__ bias, u16* __restrict__ vT) {
    __shared__ __attribute__((aligned(16))) u16 Ab[4096], Bb[4096];
    const int tid = threadIdx.x, wave = tid >> 6, lane = tid & 63;
    const int l31 = lane & 31, lh = lane >> 5;
    const int wy = wave >> 1, wx = wave & 1;
    const int M0 = blockIdx.y * 128, N0 = blockIdx.x * 128;
    const u16* Ag = Wbf + (long)M0 * DM;
    const u16* Bg = Kbf + (long)N0 * DM;

    const int u0 = wave * 2;
    const int rA0 = u0 * 16 + (lane >> 2);
    const int kcg = (lane & 3) ^ ((lane >> 3) & 3);

    f32x16 acc[2][2];
#pragma unroll
    for (int i = 0; i < 2; ++i)
#pragma unroll
        for (int j = 0; j < 2; ++j)
#pragma unroll
            for (int e = 0; e < 16; ++e) acc[i][j][e] = 0.f;

    for (int kt = 0; kt < 16; ++kt) {
        const int k0 = kt * 32;
        __syncthreads();
        STAGE(Ag, DM, Bg, DM, k0);
        __syncthreads();
#pragma unroll
        for (int ks = 0; ks < 2; ++ks) {
            const int kc = ks * 2 + lh;
            bf16x8 a0 = fragld(Ab, wy * 64 + l31, kc);
            bf16x8 a1 = fragld(Ab, wy * 64 + 32 + l31, kc);
            bf16x8 b0 = fragld(Bb, wx * 64 + l31, kc);
            bf16x8 b1 = fragld(Bb, wx * 64 + 32 + l31, kc);
            acc[0][0] = MFMA32(a0, b0, acc[0][0]);
            acc[0][1] = MFMA32(a0, b1, acc[0][1]);
            acc[1][0] = MFMA32(a1, b0, acc[1][0]);
            acc[1][1] = MFMA32(a1, b1, acc[1][1]);
        }
    }
#pragma unroll
    for (int mi = 0; mi < 2; ++mi) {
#pragma unroll
        for (int reg = 0; reg < 16; ++reg) {
            int e = M0 + wy * 64 + mi * 32 + ROWOFF(reg, lh);
            float bv = bias[e];
#pragma unroll
            for (int ni = 0; ni < 2; ++ni) {
                int g = N0 + wx * 64 + ni * 32 + l31;
                float x = acc[mi][ni][reg] + bv;
                float v = x > 0.f ? x : (__expf(x) - 1.f);
                vT[(long)e * GTOT + g] = f2bf(v);
            }
        }
    }
}

// -------- kernel 4: O = diag(1/max(||S_row||,eps)) * (S V), 128x128 R3 structure ------
// Per batch: M = 2048, N = 512 (d), K = 2048. A = S (bf16), B^T = vT.
__global__ __launch_bounds__(256, 4) void k_pv(
    const u16* __restrict__ Sbuf, const u16* __restrict__ vT,
    const float* __restrict__ ssbuf, float* __restrict__ Out) {
    __shared__ __attribute__((aligned(16))) u16 Ab[4096], Bb[4096];
    __shared__ float sc[128];
    const int tid = threadIdx.x, wave = tid >> 6, lane = tid & 63;
    const int l31 = lane & 31, lh = lane >> 5;
    const int wy = wave >> 1, wx = wave & 1;
    const int b = blockIdx.z;
    const int M0 = blockIdx.y * 128, N0 = blockIdx.x * 128;
    const u16* Ag = Sbuf + (long)(b * NSEQ + M0) * NSEQ;
    const u16* Bg = vT + (long)N0 * GTOT + b * NSEQ;

    if (tid < 128) {
        float v = ssbuf[b * NSEQ + M0 + tid];
        sc[tid] = 1.f / fmaxf(sqrtf(v), EPSN);
    }

    const int u0 = wave * 2;
    const int rA0 = u0 * 16 + (lane >> 2);
    const int kcg = (lane & 3) ^ ((lane >> 3) & 3);

    f32x16 acc[2][2];
#pragma unroll
    for (int i = 0; i < 2; ++i)
#pragma unroll
        for (int j = 0; j < 2; ++j)
#pragma unroll
            for (int e = 0; e < 16; ++e) acc[i][j][e] = 0.f;

    for (int kt = 0; kt < 64; ++kt) {
        const int k0 = kt * 32;
        __syncthreads();
        STAGE(Ag, NSEQ, Bg, GTOT, k0);
        __syncthreads();
#pragma unroll
        for (int ks = 0; ks < 2; ++ks) {
            const int kc = ks * 2 + lh;
            bf16x8 a0 = fragld(Ab, wy * 64 + l31, kc);
            bf16x8 a1 = fragld(Ab, wy * 64 + 32 + l31, kc);
            bf16x8 b0 = fragld(Bb, wx * 64 + l31, kc);
            bf16x8 b1 = fragld(Bb, wx * 64 + 32 + l31, kc);
            acc[0][0] = MFMA32(a0, b0, acc[0][0]);
            acc[0][1] = MFMA32(a0, b1, acc[0][1]);
            acc[1][0] = MFMA32(a1, b0, acc[1][0]);
            acc[1][1] = MFMA32(a1, b1, acc[1][1]);
        }
    }
#pragma unroll
    for (int mi = 0; mi < 2; ++mi) {
#pragma unroll
        for (int reg = 0; reg < 16; ++reg) {
            int rl = wy * 64 + mi * 32 + ROWOFF(reg, lh);
            float s = sc[rl];
            float* op = Out + ((long)b * NSEQ + M0 + rl) * DM;
#pragma unroll
            for (int ni = 0; ni < 2; ++ni) {
                int d = N0 + wx * 64 + ni * 32 + l31;
                op[d] = acc[mi][ni][reg] * s;
            }
        }
    }
}

extern "C" void kernel_launch(void* const* d_in, const int* in_sizes, int n_in,
                              void* d_out, int out_size, void* d_ws, size_t ws_size,
                              hipStream_t stream) {
    const float* X = (const float*)d_in[0];
    const float* mask = (const float*)d_in[1];
    const float* W = (const float*)d_in[2];
    const float* bias = (const float*)d_in[3];
    float* out = (float*)d_out;

    char* ws = (char*)d_ws;
    u16* Kbf = (u16*)ws;                           // 16 MiB
    u16* Wbf = (u16*)(ws + 16777216);              // 512 KiB
    u16* vT = (u16*)(ws + 17301504);               // 16 MiB
    u16* Sbuf = (u16*)(ws + 34078720);             // 64 MiB
    float* ssbuf = (float*)(ws + 101187584);       // 64 KiB
    u64* Mbits = (u64*)(ws + 101253120);           // 4 MiB (packed mask)

    k_convert<<<41232, 256, 0, stream>>>(X, W, mask, Kbf, Wbf, ssbuf, Mbits);
    k_vgemm<<<dim3(128, 4), 256, 0, stream>>>(Wbf, Kbf, bias, vT);
    k_sgemm<<<dim3(16, 16, 8), 256, 0, stream>>>(Kbf, (const u32*)Mbits, Sbuf, ssbuf);
    k_pv<<<dim3(4, 16, 8), 256, 0, stream>>>(Sbuf, vT, ssbuf, out);
}

// Round 7
// 348.138 us; speedup vs baseline: 2.8097x; 1.0655x over previous
//
#include <hip/hip_runtime.h>
#include <hip/hip_bf16.h>

#define NSEQ 2048
#define DM 512
#define BATCH 8
#define GTOT (BATCH * NSEQ)          // 16384
#define INV_T 0.044194173824159216f  // 1/sqrt(512)
#define EPSN 1e-5f

typedef __bf16 bf16_t;
typedef bf16_t bf16x8 __attribute__((ext_vector_type(8)));
typedef float f32x16 __attribute__((ext_vector_type(16)));
typedef unsigned short u16;
typedef unsigned int u32;
typedef unsigned char u8;
typedef unsigned long long u64;

__device__ __forceinline__ u16 f2bf(float f) {
    u32 u = __builtin_bit_cast(u32, f);
    u32 r = (u + 0x7FFFu + ((u >> 16) & 1u)) >> 16;
    return (u16)r;
}

// async global->LDS DMA, 16 B per lane. LDS dest = wave-uniform base + lane*16 B.
__device__ __forceinline__ void async16(const u16* g, u16* l) {
    __builtin_amdgcn_global_load_lds(
        (const __attribute__((address_space(1))) u32*)g,
        (__attribute__((address_space(3))) u32*)l, 16, 0, 0);
}

// BK=64 LDS tile: rows x 64 k-elems (128 B rows), 8 16-B chunks XOR-swizzled by ((row>>1)&7).
__device__ __forceinline__ bf16x8 fragld64(const u16* t, int row, int kc) {
    return *(const bf16x8*)(t + row * 64 + ((kc ^ ((row >> 1) & 7)) << 3));
}

#define MFMA32(a, b, c) __builtin_amdgcn_mfma_f32_32x32x16_bf16(a, b, c, 0, 0, 0)
#define ROWOFF(reg, lh) (((reg) & 3) + 8 * ((reg) >> 2) + 4 * (lh))

// BK=64 staging: 8 issues/thread (4 A + 4 B). Issue u = wave*4+j covers LDS rows
// u*8..u*8+7; lane supplies row u*8+(lane>>3), chunk (lane&7), fetching the
// global chunk that fragld64's XOR expects at that slot.
#define STAGE64(Ag, ldA, Bg, ldB, k0)                                            \
    do {                                                                         \
        _Pragma("unroll") for (int j = 0; j < 4; ++j) {                          \
            const int cg = (lane & 7) ^ ((j * 4 + (lane >> 4)) & 7);             \
            const int dst = (wave * 4 + j) * 512 + lane * 8;                     \
            async16((Ag) + (long)(rS + j * 8) * (ldA) + (k0) + cg * 8, Ab + dst);\
            async16((Bg) + (long)(rS + j * 8) * (ldB) + (k0) + cg * 8, Bb + dst);\
        }                                                                        \
    } while (0)

// ---------------- kernel 1: f32 -> bf16 of X and W; zero ssbuf ----------------
__global__ __launch_bounds__(256) void k_convert(
    const float* __restrict__ X, const float* __restrict__ W,
    u16* __restrict__ Kbf, u16* __restrict__ Wbf, float* __restrict__ ssbuf) {
    const long NK = (long)GTOT * DM / 4;  // 2097152
    const long NW = (long)DM * DM / 4;    // 65536
    const long NS = GTOT / 4;             // 4096
    long i = (long)blockIdx.x * 256 + threadIdx.x;
    if (i < NK) {
        float4 f = ((const float4*)X)[i];
        ushort4 o;
        o.x = f2bf(f.x); o.y = f2bf(f.y); o.z = f2bf(f.z); o.w = f2bf(f.w);
        ((ushort4*)Kbf)[i] = o;
    } else if (i < NK + NW) {
        long j = i - NK;
        float4 f = ((const float4*)W)[j];
        ushort4 o;
        o.x = f2bf(f.x); o.y = f2bf(f.y); o.z = f2bf(f.z); o.w = f2bf(f.w);
        ((ushort4*)Wbf)[j] = o;
    } else if (i < NK + NW + NS) {
        ((float4*)ssbuf)[i - NK - NW] = (float4){0.f, 0.f, 0.f, 0.f};
    }
}

// ------------- kernel 1b: bit-pack mask, float4 loads + LDS nibble assembly -------------
// Each block: 1024 mask elems -> 16 u64 words.
__global__ __launch_bounds__(256) void k_maskpack(
    const float* __restrict__ mask, u64* __restrict__ Mbits) {
    __shared__ u8 nib[256];
    const int tid = threadIdx.x;
    const long fbase = (long)blockIdx.x * 256 + tid;  // float4 index
    float4 f = ((const float4*)mask)[fbase];
    unsigned n = (f.x != 0.f ? 1u : 0u) | (f.y != 0.f ? 2u : 0u) |
                 (f.z != 0.f ? 4u : 0u) | (f.w != 0.f ? 8u : 0u);
    nib[tid] = (u8)n;
    __syncthreads();
    if (tid < 16) {
        u64 w = 0;
#pragma unroll
        for (int i = 0; i < 16; ++i) w |= (u64)nib[tid * 16 + i] << (i * 4);
        Mbits[(long)blockIdx.x * 16 + tid] = w;
    }
}

// --- kernel 2: S = bitmask .* (X X^T) * INV_T (bf16) + row sum-of-squares ---
// 128x128 tile, BK=64, 256 thr, 4 waves (2x2), wave tile 64x64.
__global__ __launch_bounds__(256, 4) void k_sgemm(
    const u16* __restrict__ Kbf, const u32* __restrict__ Mw,
    u16* __restrict__ Sbuf, float* __restrict__ ssbuf) {
    __shared__ __attribute__((aligned(16))) u16 Ab[8192], Bb[8192];
    const int tid = threadIdx.x, wave = tid >> 6, lane = tid & 63;
    const int l31 = lane & 31, lh = lane >> 5;
    const int wy = wave >> 1, wx = wave & 1;
    const int b = blockIdx.z;
    const int M0 = blockIdx.y * 128, N0 = blockIdx.x * 128;
    const u16* Ag = Kbf + (long)(b * NSEQ + M0) * DM;
    const u16* Bg = Kbf + (long)(b * NSEQ + N0) * DM;
    const u32* Mb = Mw + (long)b * NSEQ * 64;  // 64 u32 words per row

    const int rS = wave * 32 + (lane >> 3);

    f32x16 acc[2][2];
#pragma unroll
    for (int i = 0; i < 2; ++i)
#pragma unroll
        for (int j = 0; j < 2; ++j)
#pragma unroll
            for (int e = 0; e < 16; ++e) acc[i][j][e] = 0.f;

    for (int kt = 0; kt < 8; ++kt) {
        const int k0 = kt * 64;
        __syncthreads();
        STAGE64(Ag, DM, Bg, DM, k0);
        __syncthreads();
#pragma unroll
        for (int ks = 0; ks < 4; ++ks) {
            const int kc = ks * 2 + lh;
            bf16x8 a0 = fragld64(Ab, wy * 64 + l31, kc);
            bf16x8 a1 = fragld64(Ab, wy * 64 + 32 + l31, kc);
            bf16x8 b0 = fragld64(Bb, wx * 64 + l31, kc);
            bf16x8 b1 = fragld64(Bb, wx * 64 + 32 + l31, kc);
            acc[0][0] = MFMA32(a0, b0, acc[0][0]);
            acc[0][1] = MFMA32(a0, b1, acc[0][1]);
            acc[1][0] = MFMA32(a1, b0, acc[1][0]);
            acc[1][1] = MFMA32(a1, b1, acc[1][1]);
        }
    }
    // epilogue: bitmask multiply, bf16 store, per-row sum-of-squares -> atomicAdd
#pragma unroll
    for (int mi = 0; mi < 2; ++mi) {
#pragma unroll
        for (int reg = 0; reg < 16; ++reg) {
            int rl = M0 + wy * 64 + mi * 32 + ROWOFF(reg, lh);
            long rg = (long)b * NSEQ + rl;
            float v = 0.f;
#pragma unroll
            for (int ni = 0; ni < 2; ++ni) {
                int cg = N0 + wx * 64 + ni * 32 + l31;
                u32 w = Mb[(long)rl * 64 + (cg >> 5)];
                float s = ((w >> l31) & 1u) ? acc[mi][ni][reg] * INV_T : 0.f;
                v += s * s;
                Sbuf[rg * NSEQ + cg] = f2bf(s);
            }
            v += __shfl_xor(v, 1, 32);
            v += __shfl_xor(v, 2, 32);
            v += __shfl_xor(v, 4, 32);
            v += __shfl_xor(v, 8, 32);
            v += __shfl_xor(v, 16, 32);
            if (l31 == 0) atomicAdd(&ssbuf[rg], v);
        }
    }
}

// ------------- kernel 3: vT[e][g] = elu(W X^T + b), 128x128 BK=64 -------------
__global__ __launch_bounds__(256, 4) void k_vgemm(
    const u16* __restrict__ Wbf, const u16* __restrict__ Kbf,
    const float* __restrict__ bias, u16* __restrict__ vT) {
    __shared__ __attribute__((aligned(16))) u16 Ab[8192], Bb[8192];
    const int tid = threadIdx.x, wave = tid >> 6, lane = tid & 63;
    const int l31 = lane & 31, lh = lane >> 5;
    const int wy = wave >> 1, wx = wave & 1;
    const int M0 = blockIdx.y * 128, N0 = blockIdx.x * 128;
    const u16* Ag = Wbf + (long)M0 * DM;
    const u16* Bg = Kbf + (long)N0 * DM;

    const int rS = wave * 32 + (lane >> 3);

    f32x16 acc[2][2];
#pragma unroll
    for (int i = 0; i < 2; ++i)
#pragma unroll
        for (int j = 0; j < 2; ++j)
#pragma unroll
            for (int e = 0; e < 16; ++e) acc[i][j][e] = 0.f;

    for (int kt = 0; kt < 8; ++kt) {
        const int k0 = kt * 64;
        __syncthreads();
        STAGE64(Ag, DM, Bg, DM, k0);
        __syncthreads();
#pragma unroll
        for (int ks = 0; ks < 4; ++ks) {
            const int kc = ks * 2 + lh;
            bf16x8 a0 = fragld64(Ab, wy * 64 + l31, kc);
            bf16x8 a1 = fragld64(Ab, wy * 64 + 32 + l31, kc);
            bf16x8 b0 = fragld64(Bb, wx * 64 + l31, kc);
            bf16x8 b1 = fragld64(Bb, wx * 64 + 32 + l31, kc);
            acc[0][0] = MFMA32(a0, b0, acc[0][0]);
            acc[0][1] = MFMA32(a0, b1, acc[0][1]);
            acc[1][0] = MFMA32(a1, b0, acc[1][0]);
            acc[1][1] = MFMA32(a1, b1, acc[1][1]);
        }
    }
#pragma unroll
    for (int mi = 0; mi < 2; ++mi) {
#pragma unroll
        for (int reg = 0; reg < 16; ++reg) {
            int e = M0 + wy * 64 + mi * 32 + ROWOFF(reg, lh);
            float bv = bias[e];
#pragma unroll
            for (int ni = 0; ni < 2; ++ni) {
                int g = N0 + wx * 64 + ni * 32 + l31;
                float x = acc[mi][ni][reg] + bv;
                float v = x > 0.f ? x : (__expf(x) - 1.f);
                vT[(long)e * GTOT + g] = f2bf(v);
            }
        }
    }
}

// -------- kernel 4: O = diag(1/max(||S_row||,eps)) * (S V), 128x128 BK=64 ------
// Per batch: M = 2048, N = 512 (d), K = 2048. A = S (bf16), B^T = vT.
__global__ __launch_bounds__(256, 4) void k_pv(
    const u16* __restrict__ Sbuf, const u16* __restrict__ vT,
    const float* __restrict__ ssbuf, float* __restrict__ Out) {
    __shared__ __attribute__((aligned(16))) u16 Ab[8192], Bb[8192];
    __shared__ float sc[128];
    const int tid = threadIdx.x, wave = tid >> 6, lane = tid & 63;
    const int l31 = lane & 31, lh = lane >> 5;
    const int wy = wave >> 1, wx = wave & 1;
    const int b = blockIdx.z;
    const int M0 = blockIdx.y * 128, N0 = blockIdx.x * 128;
    const u16* Ag = Sbuf + (long)(b * NSEQ + M0) * NSEQ;
    const u16* Bg = vT + (long)N0 * GTOT + b * NSEQ;

    if (tid < 128) {
        float v = ssbuf[b * NSEQ + M0 + tid];
        sc[tid] = 1.f / fmaxf(sqrtf(v), EPSN);
    }

    const int rS = wave * 32 + (lane >> 3);

    f32x16 acc[2][2];
#pragma unroll
    for (int i = 0; i < 2; ++i)
#pragma unroll
        for (int j = 0; j < 2; ++j)
#pragma unroll
            for (int e = 0; e < 16; ++e) acc[i][j][e] = 0.f;

    for (int kt = 0; kt < 32; ++kt) {
        const int k0 = kt * 64;
        __syncthreads();
        STAGE64(Ag, NSEQ, Bg, GTOT, k0);
        __syncthreads();
#pragma unroll
        for (int ks = 0; ks < 4; ++ks) {
            const int kc = ks * 2 + lh;
            bf16x8 a0 = fragld64(Ab, wy * 64 + l31, kc);
            bf16x8 a1 = fragld64(Ab, wy * 64 + 32 + l31, kc);
            bf16x8 b0 = fragld64(Bb, wx * 64 + l31, kc);
            bf16x8 b1 = fragld64(Bb, wx * 64 + 32 + l31, kc);
            acc[0][0] = MFMA32(a0, b0, acc[0][0]);
            acc[0][1] = MFMA32(a0, b1, acc[0][1]);
            acc[1][0] = MFMA32(a1, b0, acc[1][0]);
            acc[1][1] = MFMA32(a1, b1, acc[1][1]);
        }
    }
#pragma unroll
    for (int mi = 0; mi < 2; ++mi) {
#pragma unroll
        for (int reg = 0; reg < 16; ++reg) {
            int rl = wy * 64 + mi * 32 + ROWOFF(reg, lh);
            float s = sc[rl];
            float* op = Out + ((long)b * NSEQ + M0 + rl) * DM;
#pragma unroll
            for (int ni = 0; ni < 2; ++ni) {
                int d = N0 + wx * 64 + ni * 32 + l31;
                op[d] = acc[mi][ni][reg] * s;
            }
        }
    }
}

extern "C" void kernel_launch(void* const* d_in, const int* in_sizes, int n_in,
                              void* d_out, int out_size, void* d_ws, size_t ws_size,
                              hipStream_t stream) {
    const float* X = (const float*)d_in[0];
    const float* mask = (const float*)d_in[1];
    const float* W = (const float*)d_in[2];
    const float* bias = (const float*)d_in[3];
    float* out = (float*)d_out;

    char* ws = (char*)d_ws;
    u16* Kbf = (u16*)ws;                           // 16 MiB
    u16* Wbf = (u16*)(ws + 16777216);              // 512 KiB
    u16* vT = (u16*)(ws + 17301504);               // 16 MiB
    u16* Sbuf = (u16*)(ws + 34078720);             // 64 MiB
    float* ssbuf = (float*)(ws + 101187584);       // 64 KiB
    u64* Mbits = (u64*)(ws + 101253120);           // 4 MiB (packed mask)

    k_convert<<<8464, 256, 0, stream>>>(X, W, Kbf, Wbf, ssbuf);
    k_maskpack<<<32768, 256, 0, stream>>>(mask, Mbits);
    k_vgemm<<<dim3(128, 4), 256, 0, stream>>>(Wbf, Kbf, bias, vT);
    k_sgemm<<<dim3(16, 16, 8), 256, 0, stream>>>(Kbf, (const u32*)Mbits, Sbuf, ssbuf);
    k_pv<<<dim3(4, 16, 8), 256, 0, stream>>>(Sbuf, vT, ssbuf, out);
}